// Round 7
// baseline (88.999 us; speedup 1.0000x reference)
//
#include <hip/hip_runtime.h>

#define I_FEAT 256
#define O_FEAT 512
#define NSEG   8
#define KDIM   (I_FEAT * NSEG)   // 2048
#define KTOT   (2 * KDIM)        // 4096 (A-part || bias-part)
#define KC_N   (KTOT / 32)       // 128 K32-chunks

typedef _Float16 half8   __attribute__((ext_vector_type(8)));
typedef float    floatx4 __attribute__((ext_vector_type(4)));
typedef uint32_t uintx4  __attribute__((ext_vector_type(4)));

// ---------------- Kernel 1: prep (pack_bfrag ∪ fused LN->Am), bid-split ----------------
__global__ __launch_bounds__(256) void prep(
    const float* __restrict__ x,
    const float* __restrict__ Aw,
    const float* __restrict__ Bw,
    const float* __restrict__ gamma,
    const float* __restrict__ beta,
    uint4* __restrict__ Bf,
    uint2* __restrict__ Am,
    int Bn, int pbTot)
{
    __shared__ uint32_t smem[16 * 260];   // 16640 B, reused by both paths
    const int t   = threadIdx.x;
    const int bid = blockIdx.x;

    if (bid < pbTot) {
        // ---- weight pack path: one 64n x 64k tile -> B-fragment stream ----
        unsigned short (*T)[72] = (unsigned short(*)[72])smem;  // [n][k] f16
        const int n0 = (bid & 7) * 64;
        const int k0 = (bid >> 3) * 64;
        const float* src = (k0 < KDIM) ? (Aw + (size_t)k0 * O_FEAT)
                                       : (Bw + (size_t)(k0 - KDIM) * O_FEAT);
        #pragma unroll
        for (int s = 0; s < 4; ++s) {
            int e  = s * 1024 + t * 4;
            int kl = e >> 6, nl = e & 63;
            const float4 v = *(const float4*)(src + (size_t)kl * O_FEAT + n0 + nl);
            T[nl + 0][kl] = __builtin_bit_cast(unsigned short, (_Float16)v.x);
            T[nl + 1][kl] = __builtin_bit_cast(unsigned short, (_Float16)v.y);
            T[nl + 2][kl] = __builtin_bit_cast(unsigned short, (_Float16)v.z);
            T[nl + 3][kl] = __builtin_bit_cast(unsigned short, (_Float16)v.w);
        }
        __syncthreads();

        const int lane = t & 63, lane16 = lane & 15, quad = lane >> 4;
        const int sub  = t >> 6;
        #pragma unroll
        for (int f = 0; f < 2; ++f) {
            const int combo = sub * 2 + f;       // 0..7
            const int n16g  = combo & 3;
            const int kch   = combo >> 2;
            const int nl = n16g * 16 + lane16;
            const int kl = kch * 32 + quad * 8;
            const uint4 val = *(const uint4*)&T[nl][kl];
            const int n16t = (n0 >> 4) + n16g;
            const int kc   = (k0 >> 5) + kch;
            Bf[((size_t)n16t * KC_N + kc) * 64 + lane] = val;
        }
    } else {
        // ---- LN -> Am path: one mt16 (16 rows), 16 threads per row ----
        uint32_t (*M)[260] = (uint32_t(*)[260])smem;   // [row][feat]
        const int mt16 = bid - pbTot;
        const int rr   = t >> 4;
        const int c16  = t & 15;
        const int row  = mt16 * 16 + rr;
        const bool ok  = (row < Bn);

        float4 v[4];
        const float* xr = x + (size_t)row * I_FEAT + c16 * 16;
        #pragma unroll
        for (int j = 0; j < 4; ++j)
            v[j] = ok ? *(const float4*)(xr + j * 4) : make_float4(0.f, 0.f, 0.f, 0.f);

        float sum = 0.f, sq = 0.f;
        #pragma unroll
        for (int j = 0; j < 4; ++j) {
            sum += v[j].x + v[j].y + v[j].z + v[j].w;
            sq  += v[j].x * v[j].x + v[j].y * v[j].y
                 + v[j].z * v[j].z + v[j].w * v[j].w;
        }
        #pragma unroll
        for (int mask = 1; mask < 16; mask <<= 1) {
            sum += __shfl_xor(sum, mask);
            sq  += __shfl_xor(sq,  mask);
        }
        const float mu  = sum * (1.0f / I_FEAT);
        const float var = sq * (1.0f / I_FEAT) - mu * mu;
        const float rs  = rsqrtf(var + 1e-5f);

        #pragma unroll
        for (int j = 0; j < 4; ++j) {
            const float4 g4 = *(const float4*)(gamma + c16 * 16 + j * 4);
            const float4 b4 = *(const float4*)(beta  + c16 * 16 + j * 4);
            const float vv[4] = { v[j].x, v[j].y, v[j].z, v[j].w };
            const float gg[4] = { g4.x, g4.y, g4.z, g4.w };
            const float bb[4] = { b4.x, b4.y, b4.z, b4.w };
            #pragma unroll
            for (int e = 0; e < 4; ++e) {
                const int c = c16 * 16 + j * 4 + e;
                float xn = (vv[e] - mu) * rs * gg[e] + bb[e];
                float fi = (xn + 1.0f) * 4.0f;   // (xn - GRID_MIN)/STEP, exact fp32
                int seg = (int)fi;                // trunc == jnp astype(int32)
                seg = seg < 0 ? 0 : (seg > NSEG - 1 ? NSEG - 1 : seg);
                _Float16 hx = (_Float16)xn;
                M[rr][c] = ((uint32_t)seg << 16)
                         | (uint32_t)__builtin_bit_cast(unsigned short, hx);
            }
        }
        __syncthreads();

        // emit Am: word(m,w): w<256 -> meta; w>=256 -> (seg<<16 | f16(1.0))
        const int lane = t & 63, g = t >> 6;
        const int m_local = lane & 15, quad = lane >> 4;
        uint2* dst = Am + (size_t)mt16 * 64 * 64 + lane;
        #pragma unroll
        for (int kk = 0; kk < 16; ++kk) {
            const int kcp = g * 16 + kk;
            const int w0  = kcp * 8 + quad;
            const int w1  = w0 + 4;
            const uint32_t u0 = M[m_local][w0 & 255];
            const uint32_t u1 = M[m_local][w1 & 255];
            const uint32_t a  = (w0 >> 8) ? ((u0 & 0xFFFF0000u) | 0x3C00u) : u0;
            const uint32_t b  = (w1 >> 8) ? ((u1 & 0xFFFF0000u) | 0x3C00u) : u1;
            dst[(size_t)kcp * 64] = make_uint2(a, b);
        }
    }
}

// ---------------- Kernel 2: m97-style MFMA GEMM ----------------
// 512 thr = 8 waves (4m x 2n), block 64m x 64n, serial K.
// B-frags: global_load_lds (16B) -> LDS dbuf, ds_read_b128 consume.
// A-frags: one-hot built in-register from slab-prefetched meta uint2.
static __device__ __forceinline__ half8 build_onehot(uint32_t u) {
    const uint32_t xb  = u & 0xFFFFu;
    const uint32_t seg = u >> 16;
    const uint64_t oh  = (uint64_t)xb << ((seg & 3u) << 4);
    const uint64_t lo  = (seg < 4u) ? oh : 0ull;
    const uint64_t hi  = (seg < 4u) ? 0ull : oh;
    uintx4 w;
    w[0] = (uint32_t)lo; w[1] = (uint32_t)(lo >> 32);
    w[2] = (uint32_t)hi; w[3] = (uint32_t)(hi >> 32);
    return __builtin_bit_cast(half8, w);
}

__global__ __launch_bounds__(512, 2) void kan_gemm(
    const uint2* __restrict__ Am,
    const uint4* __restrict__ Bf,
    float* __restrict__ out,
    int Bn)
{
    __shared__ uint4 bbuf[2][32][64];   // 64 KB: [buf][cell = n16l*8 + kcl][lane]

    const int t      = threadIdx.x;
    const int wave   = t >> 6, lane = t & 63;
    const int wm     = wave >> 1;        // m16 within block (0..3)
    const int wn     = wave & 1;         // n32 within block (0..1)
    const int lane16 = lane & 15, quad = lane >> 4;

    const int nb = blockIdx.x;           // n-block (64 cols); XCD = bid%8 = nb
    const int mb = blockIdx.y;           // m-block (64 rows)

    const uint2* pa = Am + ((size_t)(mb * 4 + wm) * 64) * 64 + lane;

    floatx4 acc0 = {}, acc1 = {};

    // stage slab s (8 kc) into bbuf[b]: wave stages 4 cells (j, kcl=wave)
    auto stage = [&](int s, int b) {
        const int kc0 = s * 8;
        #pragma unroll
        for (int j = 0; j < 4; ++j) {
            const int idx  = j * 8 + wave;
            const int n16l = idx >> 3, kcl = idx & 7;
            const uint4* g = Bf
                + ((size_t)((nb * 4 + n16l) * KC_N + kc0 + kcl)) * 64 + lane;
            __builtin_amdgcn_global_load_lds(
                (const __attribute__((address_space(1))) uint32_t*)g,
                (__attribute__((address_space(3))) uint32_t*)&bbuf[b][idx][lane],
                16, 0, 0);
        }
    };

    uint2 cur[4], nxt[4];
    stage(0, 0);
    #pragma unroll
    for (int c = 0; c < 4; ++c) cur[c] = pa[(size_t)c * 64];
    __syncthreads();   // drains vmcnt -> slab 0 ready

    for (int s = 0; s < 16; ++s) {
        const int b = s & 1;
        if (s < 15) {
            stage(s + 1, b ^ 1);                       // DMA flies under compute
            #pragma unroll
            for (int c = 0; c < 4; ++c) nxt[c] = pa[(size_t)((s + 1) * 4 + c) * 64];
        }
        #pragma unroll
        for (int c = 0; c < 4; ++c) {                  // 4 kc-pairs per slab
            const int kcl0 = c * 2;
            const half8 b00 = __builtin_bit_cast(half8, bbuf[b][(wn * 2 + 0) * 8 + kcl0][lane]);
            const half8 b10 = __builtin_bit_cast(half8, bbuf[b][(wn * 2 + 1) * 8 + kcl0][lane]);
            const half8 b01 = __builtin_bit_cast(half8, bbuf[b][(wn * 2 + 0) * 8 + kcl0 + 1][lane]);
            const half8 b11 = __builtin_bit_cast(half8, bbuf[b][(wn * 2 + 1) * 8 + kcl0 + 1][lane]);
            half8 a = build_onehot(cur[c].x);
            acc0 = __builtin_amdgcn_mfma_f32_16x16x32_f16(a, b00, acc0, 0, 0, 0);
            acc1 = __builtin_amdgcn_mfma_f32_16x16x32_f16(a, b10, acc1, 0, 0, 0);
            a = build_onehot(cur[c].y);
            acc0 = __builtin_amdgcn_mfma_f32_16x16x32_f16(a, b01, acc0, 0, 0, 0);
            acc1 = __builtin_amdgcn_mfma_f32_16x16x32_f16(a, b11, acc1, 0, 0, 0);
        }
        __syncthreads();   // drains vmcnt -> slab s+1 ready; bbuf[b] reads done
        #pragma unroll
        for (int c = 0; c < 4; ++c) cur[c] = nxt[c];
    }

    // epilogue: C/D layout col=lane&15, row=quad*4+reg
    const int grow0 = mb * 64 + wm * 16 + quad * 4;
    const int gcol  = nb * 64 + wn * 32 + lane16;
    #pragma unroll
    for (int r = 0; r < 4; ++r) {
        const int grow = grow0 + r;
        if (grow < Bn) {
            out[(size_t)grow * O_FEAT + gcol]      = acc0[r];
            out[(size_t)grow * O_FEAT + gcol + 16] = acc1[r];
        }
    }
}

extern "C" void kernel_launch(void* const* d_in, const int* in_sizes, int n_in,
                              void* d_out, int out_size, void* d_ws, size_t ws_size,
                              hipStream_t stream) {
    const float* x   = (const float*)d_in[0];
    const float* Aw  = (const float*)d_in[1];
    const float* Bw  = (const float*)d_in[2];
    const float* gam = (const float*)d_in[3];
    const float* bet = (const float*)d_in[4];
    float* out       = (float*)d_out;

    const int Bn      = in_sizes[0] / I_FEAT;
    const int mt16Tot = (Bn + 15) / 16;
    const int mb64Tot = (Bn + 63) / 64;
    const int pbTot   = (O_FEAT / 64) * (KTOT / 64);   // 512

    // ws: Bf 4MB | Am (mt16Tot*64*64*8B)
    uint4* Bf = (uint4*)d_ws;
    uint2* Am = (uint2*)(Bf + (size_t)(O_FEAT / 16) * KC_N * 64);

    hipLaunchKernelGGL(prep, dim3(pbTot + mt16Tot), dim3(256), 0, stream,
                       x, Aw, Bw, gam, bet, Bf, Am, Bn, pbTot);
    hipLaunchKernelGGL(kan_gemm, dim3(O_FEAT / 64, mb64Tot), dim3(512), 0, stream,
                       Am, Bf, out, Bn);
}